// Round 2
// baseline (1831.625 us; speedup 1.0000x reference)
//
#include <hip/hip_runtime.h>

typedef _Float16 f16x8 __attribute__((ext_vector_type(8)));
typedef float f32x4 __attribute__((ext_vector_type(4)));

// ---------- 3x3 SAME conv + ReLU, fp32 in/out; optional split-fp16 output ----------
// tile: 8 rows x 64 cols per block; grid = B * 8; CIN processed in <=16-ch phases
template<int CIN, int COUT, bool SPLIT>
__global__ __launch_bounds__(256)
void conv3x3_f32(const float* __restrict__ in, const float* __restrict__ w,
                 const float* __restrict__ bias, float* __restrict__ out32,
                 _Float16* __restrict__ outh, _Float16* __restrict__ outl)
{
  constexpr int CT = (CIN < 16) ? CIN : 16;
  const int bi = blockIdx.x;
  const int b = bi >> 3;
  const int r0 = (bi & 7) << 3;
  const int tid = threadIdx.x;
  const int col = tid & 63;
  const int rowg = tid >> 6;            // 0..3 -> output rows r0+rowg*2, +1

  __shared__ float xs[CT][10][66];
  __shared__ float wsm[CT][9][16];

  for (int oc0 = 0; oc0 < COUT; oc0 += 16) {
    float acc0[16], acc1[16];
#pragma unroll
    for (int o = 0; o < 16; ++o) { acc0[o] = 0.f; acc1[o] = 0.f; }

    for (int ic0 = 0; ic0 < CIN; ic0 += CT) {
      __syncthreads();   // previous phase's compute done, xs/wsm free
      for (int idx = tid; idx < CT * 660; idx += 256) {
        const int ic = idx / 660;
        const int rem = idx - ic * 660;
        const int hr = rem / 66;
        const int hc = rem - hr * 66;
        const int gr = r0 + hr - 1, gc = hc - 1;
        float v = 0.f;
        if (gr >= 0 && gr < 64 && gc >= 0 && gc < 64)
          v = in[(size_t)(b * CIN + ic0 + ic) * 4096 + gr * 64 + gc];
        xs[ic][hr][hc] = v;
      }
      for (int idx = tid; idx < CT * 144; idx += 256) {
        const int o = idx & 15;
        const int rest = idx >> 4;
        const int tap = rest % 9;
        const int ic = rest / 9;
        wsm[ic][tap][o] = w[((size_t)(oc0 + o) * CIN + ic0 + ic) * 9 + tap];
      }
      __syncthreads();

      for (int ic = 0; ic < CT; ++ic) {
        float xv[4][3];
#pragma unroll
        for (int rr = 0; rr < 4; ++rr)
#pragma unroll
          for (int cc = 0; cc < 3; ++cc)
            xv[rr][cc] = xs[ic][rowg * 2 + rr][col + cc];
#pragma unroll
        for (int ty = 0; ty < 3; ++ty)
#pragma unroll
          for (int tx = 0; tx < 3; ++tx) {
            const float x0 = xv[ty][tx], x1 = xv[ty + 1][tx];
#pragma unroll
            for (int o = 0; o < 16; ++o) {
              const float wv = wsm[ic][ty * 3 + tx][o];
              acc0[o] = fmaf(x0, wv, acc0[o]);
              acc1[o] = fmaf(x1, wv, acc1[o]);
            }
          }
      }
    }

    const int p0 = (r0 + rowg * 2) * 64 + col;
#pragma unroll
    for (int o = 0; o < 16; ++o) {
      const float bv = bias[oc0 + o];
      const float v0 = fmaxf(acc0[o] + bv, 0.f);
      const float v1 = fmaxf(acc1[o] + bv, 0.f);
      const size_t oi = (size_t)(b * COUT + oc0 + o) * 4096 + p0;
      if (SPLIT) {
        const _Float16 h0 = (_Float16)v0;
        const _Float16 h1 = (_Float16)v1;
        outh[oi]      = h0;  outl[oi]      = (_Float16)((v0 - (float)h0) * 2048.0f);
        outh[oi + 64] = h1;  outl[oi + 64] = (_Float16)((v1 - (float)h1) * 2048.0f);
      } else {
        out32[oi]      = v0;
        out32[oi + 64] = v1;
      }
    }
  }
}

// ---------- fc1: C[256,1024] = A[256,262144] * W[262144,1024], split-fp16 = fp32-grade ----------
// A pre-split (Ahi,Alo fp16), W split in-register from fp32 load.
// grid (8 ntiles, 64 sk), block 512 (8 waves: 4Mx2N of 64x64). BK=32, 3 MFMA per frag pair.
__global__ __launch_bounds__(512)
void fc1_gemm_split(const _Float16* __restrict__ Ahi, const _Float16* __restrict__ Alo,
                    const float* __restrict__ W, float* __restrict__ P)
{
  const int nt = blockIdx.x;
  const int sk = blockIdx.y;
  const int nc0 = nt * 128;
  const int tid = threadIdx.x;
  const int lane = tid & 63;
  const int wid = tid >> 6;
  const int wm = wid >> 1;
  const int wn = wid & 1;

  __shared__ _Float16 Ash[256][40];   // 80B pitch: 16B-aligned rows, 8-bank rotation
  __shared__ _Float16 Asl[256][40];
  __shared__ _Float16 Bsh[128][40];   // Bs[n][k]
  __shared__ _Float16 Bsl[128][40];

  f32x4 accm[4][4] = {};
  f32x4 accc[4][4] = {};

  const int arow = tid >> 1;
  const int ako  = (tid & 1) << 4;
  const int nl = tid & 127;
  const int kq = tid >> 7;

  for (int it = 0; it < 128; ++it) {
    const size_t k0 = (size_t)sk * 4096 + it * 32;
    __syncthreads();
    // stage A tile [256][32] hi+lo
    {
      const _Float16* ph = Ahi + (size_t)arow * 262144 + k0 + ako;
      const _Float16* pl = Alo + (size_t)arow * 262144 + k0 + ako;
      *(uint4*)&Ash[arow][ako]     = *(const uint4*)ph;
      *(uint4*)&Ash[arow][ako + 8] = *(const uint4*)(ph + 8);
      *(uint4*)&Asl[arow][ako]     = *(const uint4*)pl;
      *(uint4*)&Asl[arow][ako + 8] = *(const uint4*)(pl + 8);
    }
    // stage W tile [32k][128n] fp32 -> split hi/lo fp16, Bs[n][k]
    {
      const float* wp = W + (k0 + kq * 8) * 1024 + nc0 + nl;
      f16x8 hv, lv;
#pragma unroll
      for (int i = 0; i < 8; ++i) {
        const float f = wp[(size_t)i * 1024];
        const _Float16 h = (_Float16)f;
        hv[i] = h;
        lv[i] = (_Float16)((f - (float)h) * 2048.0f);
      }
      *(f16x8*)&Bsh[nl][kq * 8] = hv;
      *(f16x8*)&Bsl[nl][kq * 8] = lv;
    }
    __syncthreads();

    const int ks = (lane >> 4) << 3;
    f16x8 ah[4], al[4], bh[4], bl[4];
#pragma unroll
    for (int mf = 0; mf < 4; ++mf) {
      ah[mf] = *(const f16x8*)&Ash[wm * 64 + mf * 16 + (lane & 15)][ks];
      al[mf] = *(const f16x8*)&Asl[wm * 64 + mf * 16 + (lane & 15)][ks];
    }
#pragma unroll
    for (int nf = 0; nf < 4; ++nf) {
      bh[nf] = *(const f16x8*)&Bsh[wn * 64 + nf * 16 + (lane & 15)][ks];
      bl[nf] = *(const f16x8*)&Bsl[wn * 64 + nf * 16 + (lane & 15)][ks];
    }
#pragma unroll
    for (int mf = 0; mf < 4; ++mf)
#pragma unroll
      for (int nf = 0; nf < 4; ++nf) {
        accm[mf][nf] = __builtin_amdgcn_mfma_f32_16x16x32_f16(ah[mf], bh[nf], accm[mf][nf], 0, 0, 0);
        accc[mf][nf] = __builtin_amdgcn_mfma_f32_16x16x32_f16(ah[mf], bl[nf], accc[mf][nf], 0, 0, 0);
        accc[mf][nf] = __builtin_amdgcn_mfma_f32_16x16x32_f16(al[mf], bh[nf], accc[mf][nf], 0, 0, 0);
      }
  }

  // epilogue: combined partial. C/D layout: col=lane&15, row=(lane>>4)*4+r
#pragma unroll
  for (int mf = 0; mf < 4; ++mf) {
    const int rbase = wm * 64 + mf * 16 + ((lane >> 4) << 2);
#pragma unroll
    for (int nf = 0; nf < 4; ++nf) {
      const int c = nc0 + wn * 64 + nf * 16 + (lane & 15);
#pragma unroll
      for (int r = 0; r < 4; ++r)
        P[((size_t)sk * 256 + rbase + r) * 1024 + c] =
            accm[mf][nf][r] + accc[mf][nf][r] * (1.0f / 2048.0f);
    }
  }
}

// ---------- fc1 reduce: s1 = relu(sum_sk P + bias) ----------
__global__ __launch_bounds__(256)
void fc1_reduce(const float* __restrict__ P, const float* __restrict__ bias,
                float* __restrict__ s1)
{
  const int idx = blockIdx.x * 256 + threadIdx.x;  // 262144 total
  const int n = idx & 1023;
  float a = bias[n];
#pragma unroll 8
  for (int sk = 0; sk < 64; ++sk) a += P[(size_t)sk * 262144 + idx];
  s1[idx] = fmaxf(a, 0.f);
}

// ---------- fc2: s2[256,256] = relu(s1[256,1024] @ w[1024,256] + b) ----------
__global__ __launch_bounds__(256)
void fc2_k(const float* __restrict__ s1, const float* __restrict__ w,
           const float* __restrict__ b, float* __restrict__ s2)
{
  const int bb = blockIdx.x;
  const int t = threadIdx.x;
  __shared__ float xr[1024];
  for (int i = t; i < 1024; i += 256) xr[i] = s1[bb * 1024 + i];
  __syncthreads();
  float a0 = b[t], a1 = 0.f, a2 = 0.f, a3 = 0.f;
#pragma unroll 4
  for (int k = 0; k < 1024; k += 4) {
    a0 += xr[k + 0] * w[(k + 0) * 256 + t];
    a1 += xr[k + 1] * w[(k + 1) * 256 + t];
    a2 += xr[k + 2] * w[(k + 2) * 256 + t];
    a3 += xr[k + 3] * w[(k + 3) * 256 + t];
  }
  s2[bb * 256 + t] = fmaxf(a0 + a1 + a2 + a3, 0.f);
}

// ---------- gate: logits->softmax->top2 (precise expf / true div) ----------
__global__ __launch_bounds__(64)
void gate_k(const float* __restrict__ s2, const float* __restrict__ gw,
            const float* __restrict__ gb, float* __restrict__ gate_out,
            int* __restrict__ topi, float* __restrict__ topv)
{
  const int bb = blockIdx.x;
  const int l = threadIdx.x;
  float part[8] = {};
  for (int k = l; k < 256; k += 64) {
    const float x = s2[bb * 256 + k];
#pragma unroll
    for (int e = 0; e < 8; ++e) part[e] += x * gw[k * 8 + e];
  }
#pragma unroll
  for (int off = 32; off > 0; off >>= 1)
#pragma unroll
    for (int e = 0; e < 8; ++e) part[e] += __shfl_down(part[e], off);

  if (l == 0) {
    float lg[8];
    float m = -1e30f;
#pragma unroll
    for (int e = 0; e < 8; ++e) { lg[e] = part[e] + gb[e]; m = fmaxf(m, lg[e]); }
    float s = 0.f;
    float p[8];
#pragma unroll
    for (int e = 0; e < 8; ++e) { p[e] = expf(lg[e] - m); s += p[e]; }
#pragma unroll
    for (int e = 0; e < 8; ++e) { p[e] = p[e] / s; gate_out[bb * 8 + e] = p[e]; }
    // top2, first-index-wins on ties (matches lax.top_k)
    int i0 = 0;
#pragma unroll
    for (int e = 1; e < 8; ++e) if (p[e] > p[i0]) i0 = e;
    int i1 = (i0 == 0) ? 1 : 0;
#pragma unroll
    for (int e = 0; e < 8; ++e) if (e != i0 && p[e] > p[i1]) i1 = e;
    const float v0 = p[i0], v1 = p[i1];
    topi[bb * 2 + 0] = i0; topi[bb * 2 + 1] = i1;
    topv[bb * 2 + 0] = v0 / (v0 + v1); topv[bb * 2 + 1] = v1 / (v0 + v1);
  }
}

// ---------- experts (only the 2 selected per token) + weighted combine ----------
__global__ __launch_bounds__(256)
void expert_k(const float* __restrict__ s2, const float* __restrict__ w1,
              const float* __restrict__ b1, const float* __restrict__ w2,
              const float* __restrict__ b2, const int* __restrict__ topi,
              const float* __restrict__ topv, float* __restrict__ out)
{
  const int bb = blockIdx.x;
  const int t = threadIdx.x;
  __shared__ float xr[256];
  __shared__ float eh[512];
  __shared__ float partial[18][8];
  xr[t] = s2[bb * 256 + t];
  float logit = 0.f;  // used by t<18
  for (int kk = 0; kk < 2; ++kk) {
    __syncthreads();
    const int e = topi[bb * 2 + kk];
    const float tv = topv[bb * 2 + kk];
    const float* W1 = w1 + (size_t)e * 256 * 512;
    float a0 = b1[e * 512 + t], a1 = b1[e * 512 + 256 + t];
#pragma unroll 4
    for (int k = 0; k < 256; ++k) {
      const float x = xr[k];
      a0 = fmaf(x, W1[k * 512 + t], a0);
      a1 = fmaf(x, W1[k * 512 + 256 + t], a1);
    }
    eh[t] = fmaxf(a0, 0.f);
    eh[256 + t] = fmaxf(a1, 0.f);
    __syncthreads();
    if (t < 144) {
      const int a = t >> 3, q = t & 7;
      const float* W2 = w2 + (size_t)e * 512 * 18;
      float pp = 0.f;
      for (int h = q * 64; h < q * 64 + 64; ++h) pp = fmaf(eh[h], W2[h * 18 + a], pp);
      partial[a][q] = pp;
    }
    __syncthreads();
    if (t < 18) {
      float s = b2[e * 18 + t];
#pragma unroll
      for (int q = 0; q < 8; ++q) s += partial[t][q];
      logit = fmaf(tv, s, logit);
    }
  }
  if (t < 18) out[bb * 18 + t] = logit;
}

// ---------- launch ----------
extern "C" void kernel_launch(void* const* d_in, const int* in_sizes, int n_in,
                              void* d_out, int out_size, void* d_ws, size_t ws_size,
                              hipStream_t stream) {
  const float* obs     = (const float*)d_in[0];
  const float* conv1_w = (const float*)d_in[1];
  const float* conv1_b = (const float*)d_in[2];
  const float* conv2_w = (const float*)d_in[3];
  const float* conv2_b = (const float*)d_in[4];
  const float* conv3_w = (const float*)d_in[5];
  const float* conv3_b = (const float*)d_in[6];
  const float* fc1_w   = (const float*)d_in[7];
  const float* fc1_b   = (const float*)d_in[8];
  const float* fc2_w   = (const float*)d_in[9];
  const float* fc2_b   = (const float*)d_in[10];
  const float* gate_w  = (const float*)d_in[11];
  const float* gate_b  = (const float*)d_in[12];
  const float* exp_w1  = (const float*)d_in[13];
  const float* exp_b1  = (const float*)d_in[14];
  const float* exp_w2  = (const float*)d_in[15];
  const float* exp_b2  = (const float*)d_in[16];

  char* ws = (char*)d_ws;
  const size_t MB = 1ull << 20;
  float*    act1 = (float*)(ws);                    // 64 MB  [256][16][4096] f32
  float*    act2 = (float*)(ws + 64 * MB);          // 128 MB [256][32][4096] f32
  _Float16* Ahi  = (_Float16*)(ws + 192 * MB);      // 128 MB [256][262144] f16
  _Float16* Alo  = (_Float16*)(ws + 320 * MB);      // 128 MB
  float*    P    = (float*)(ws);                    // 64 MB [64][256][1024] (reuses act1)
  float*    s1   = (float*)(ws + 448 * MB);         // 1 MB
  float*    s2   = (float*)(ws + 449 * MB);         // 256 KB
  int*      topi = (int*)(ws + 450 * MB);
  float*    topv = (float*)(ws + 450 * MB + 4096);
  float*    out  = (float*)d_out;   // [256*18 logits][256*8 gate_probs]

  conv3x3_f32<1, 16, false><<<2048, 256, 0, stream>>>(obs,  conv1_w, conv1_b, act1, nullptr, nullptr);
  conv3x3_f32<16, 32, false><<<2048, 256, 0, stream>>>(act1, conv2_w, conv2_b, act2, nullptr, nullptr);
  conv3x3_f32<32, 64, true ><<<2048, 256, 0, stream>>>(act2, conv3_w, conv3_b, nullptr, Ahi, Alo);

  fc1_gemm_split<<<dim3(8, 64), 512, 0, stream>>>(Ahi, Alo, fc1_w, P);
  fc1_reduce<<<1024, 256, 0, stream>>>(P, fc1_b, s1);
  fc2_k<<<256, 256, 0, stream>>>(s1, fc2_w, fc2_b, s2);
  gate_k<<<256, 64, 0, stream>>>(s2, gate_w, gate_b, out + 256 * 18, topi, topv);
  expert_k<<<256, 256, 0, stream>>>(s2, exp_w1, exp_b1, exp_w2, exp_b2, topi, topv, out);
}

// Round 3
// 1204.453 us; speedup vs baseline: 1.5207x; 1.5207x over previous
//
#include <hip/hip_runtime.h>

typedef _Float16 f16x8 __attribute__((ext_vector_type(8)));
typedef float f32x4 __attribute__((ext_vector_type(4)));

// ================= weight prepack: OIHW fp32 -> [oc][3*KPAD] split hi/lo f16 =================
// k-order within row y: kk = tx*CIN + ic (matches NHWC contiguity), zero-padded to KPAD
__global__ void prepack_w(const float* __restrict__ w, _Float16* __restrict__ ph,
                          _Float16* __restrict__ pl, int COUT, int CIN, int KPAD)
{
  const int idx = blockIdx.x * 256 + threadIdx.x;
  const int KTOT = 3 * KPAD;
  if (idx >= COUT * KTOT) return;
  const int oc = idx / KTOT;
  const int rem = idx - oc * KTOT;
  const int y = rem / KPAD;
  const int kk = rem - y * KPAD;
  float v = 0.f;
  if (kk < 3 * CIN) {
    const int tx = kk / CIN;
    const int ic = kk - tx * CIN;
    v = w[((size_t)oc * CIN + ic) * 9 + y * 3 + tx];
  }
  const _Float16 h = (_Float16)v;
  ph[idx] = h;
  pl[idx] = (_Float16)((v - (float)h) * 2048.0f);
}

// ================= conv1: CIN=1, VALU fp32, NHWC split-f16 out =================
__global__ __launch_bounds__(256)
void conv1_k(const float* __restrict__ obs, const float* __restrict__ w,
             const float* __restrict__ bias, _Float16* __restrict__ outh,
             _Float16* __restrict__ outl)
{
  const int rg = blockIdx.x;    // 0..15, 4 rows each
  const int b = blockIdx.y;
  const int tid = threadIdx.x;
  const int lr = tid >> 6;      // 0..3
  const int col = tid & 63;
  __shared__ float xs[6][66];
  __shared__ float wb[9][16];
  for (int idx = tid; idx < 6 * 66; idx += 256) {
    const int r = idx / 66, c = idx - (idx / 66) * 66;
    const int gr = rg * 4 - 1 + r, gc = c - 1;
    xs[r][c] = (gr >= 0 && gr < 64 && gc >= 0 && gc < 64)
                   ? obs[(size_t)b * 4096 + gr * 64 + gc] : 0.f;
  }
  if (tid < 144) wb[tid / 16][tid & 15] = w[(tid & 15) * 9 + tid / 16];
  __syncthreads();
  float acc[16];
#pragma unroll
  for (int o = 0; o < 16; ++o) acc[o] = bias[o];
#pragma unroll
  for (int ty = 0; ty < 3; ++ty)
#pragma unroll
    for (int tx = 0; tx < 3; ++tx) {
      const float x = xs[lr + ty][col + tx];
#pragma unroll
      for (int o = 0; o < 16; ++o) acc[o] = fmaf(x, wb[ty * 3 + tx][o], acc[o]);
    }
  const size_t base = ((size_t)(b * 64 + rg * 4 + lr) * 64 + col) * 16;
#pragma unroll
  for (int o = 0; o < 16; ++o) {
    const float v = fmaxf(acc[o], 0.f);
    const _Float16 h = (_Float16)v;
    outh[base + o] = h;
    outl[base + o] = (_Float16)((v - (float)h) * 2048.0f);
  }
}

// ================= conv MFMA: NHWC shift-GEMM, split-f16 3-term =================
// block = 256 thr = 4 waves (wm: row of pair, wn: oc half); tile = 2 rows x 64 cols x COUT
// LDS: rows r0-1..r0+2 x 68 halo cols x CIN (+8 pad), hi+lo; staged once, 1 barrier
template<int CIN, int COUT>
__global__ __launch_bounds__(256)
void conv_mfma(const _Float16* __restrict__ inh, const _Float16* __restrict__ inl,
               const _Float16* __restrict__ wph, const _Float16* __restrict__ wpl,
               const float* __restrict__ bias,
               _Float16* __restrict__ outh, _Float16* __restrict__ outl)
{
  constexpr int KFX = (3 * CIN + 31) / 32;   // k-frags per tap-row
  constexpr int KPAD = KFX * 32;
  constexpr int KTOT = 3 * KPAD;
  constexpr int CP = CIN + 8;                // padded col pitch (bank spread)
  constexpr int NF = COUT / 32;              // n-frags per wave
  const int rp = blockIdx.x;                 // 0..31 row pair
  const int b  = blockIdx.y;
  const int r0 = rp * 2;
  const int tid = threadIdx.x;
  const int lane = tid & 63;
  const int wid = tid >> 6;
  const int wm = wid >> 1;
  const int wn = wid & 1;

  __shared__ _Float16 xh[4][68][CP];
  __shared__ _Float16 xl[4][68][CP];

  constexpr int CH = CIN / 8;
  for (int idx = tid; idx < 4 * 68 * CH; idx += 256) {
    const int r = idx / (68 * CH);
    const int rem = idx - r * 68 * CH;
    const int hc = rem / CH;
    const int ch = rem - hc * CH;
    const int gr = r0 - 1 + r;
    const int gc = hc - 1;
    uint4 vh = {0, 0, 0, 0}, vl = {0, 0, 0, 0};
    if (gr >= 0 && gr < 64 && gc >= 0 && gc < 64) {
      const size_t base = ((size_t)(b * 64 + gr) * 64 + gc) * CIN + ch * 8;
      vh = *(const uint4*)(inh + base);
      vl = *(const uint4*)(inl + base);
    }
    *(uint4*)&xh[r][hc][ch * 8] = vh;
    *(uint4*)&xl[r][hc][ch * 8] = vl;
  }
  __syncthreads();

  f32x4 accm[4][NF];
  f32x4 accc[4][NF];
#pragma unroll
  for (int mf = 0; mf < 4; ++mf)
#pragma unroll
    for (int nf = 0; nf < NF; ++nf) { accm[mf][nf] = {}; accc[mf][nf] = {}; }

  const int lm = lane & 15;
  const int ch8 = (lane >> 4) * 8;

#pragma unroll
  for (int kf = 0; kf < 3 * KFX; ++kf) {
    const int y = kf / KFX;
    const int fx = kf - y * KFX;
    const int kk = fx * 32 + ch8;
    f16x8 bh[NF], bl[NF];
#pragma unroll
    for (int nf = 0; nf < NF; ++nf) {
      const int oc = wn * (16 * NF) + nf * 16 + lm;
      bh[nf] = *(const f16x8*)(wph + (size_t)oc * KTOT + kf * 32 + ch8);
      bl[nf] = *(const f16x8*)(wpl + (size_t)oc * KTOT + kf * 32 + ch8);
    }
#pragma unroll
    for (int mf = 0; mf < 4; ++mf) {
      const int col = mf * 16 + lm;
      const f16x8 ah = *(const f16x8*)&xh[wm + y][col + kk / CIN][kk % CIN];
      const f16x8 al = *(const f16x8*)&xl[wm + y][col + kk / CIN][kk % CIN];
#pragma unroll
      for (int nf = 0; nf < NF; ++nf) {
        accm[mf][nf] = __builtin_amdgcn_mfma_f32_16x16x32_f16(ah, bh[nf], accm[mf][nf], 0, 0, 0);
        accc[mf][nf] = __builtin_amdgcn_mfma_f32_16x16x32_f16(ah, bl[nf], accc[mf][nf], 0, 0, 0);
        accc[mf][nf] = __builtin_amdgcn_mfma_f32_16x16x32_f16(al, bh[nf], accc[mf][nf], 0, 0, 0);
      }
    }
  }

  // epilogue: C/D layout col=lane&15 (n), row=(lane>>4)*4+r (m) — verified convention
  const int orow = r0 + wm;
#pragma unroll
  for (int nf = 0; nf < NF; ++nf) {
    const int oc = wn * (16 * NF) + nf * 16 + lm;
    const float bv = bias[oc];
#pragma unroll
    for (int mf = 0; mf < 4; ++mf) {
#pragma unroll
      for (int r = 0; r < 4; ++r) {
        const int x = mf * 16 + (lane >> 4) * 4 + r;
        const float v = fmaxf(accm[mf][nf][r] + accc[mf][nf][r] * (1.0f / 2048.0f) + bv, 0.f);
        const _Float16 h = (_Float16)v;
        const size_t oi = ((size_t)(b * 64 + orow) * 64 + x) * COUT + oc;
        outh[oi] = h;
        outl[oi] = (_Float16)((v - (float)h) * 2048.0f);
      }
    }
  }
}

// ================= fc1: C[256,1024] = A[256,262144](NHWC split) * W(permuted rows) =================
// grid (64 sk, 8 nt): same-sk blocks adjacent in dispatch -> same XCD -> A-slice L2-shared
__global__ __launch_bounds__(512)
void fc1_gemm_split(const _Float16* __restrict__ Ahi, const _Float16* __restrict__ Alo,
                    const float* __restrict__ W, float* __restrict__ P)
{
  const int sk = blockIdx.x;
  const int nt = blockIdx.y;
  const int nc0 = nt * 128;
  const int tid = threadIdx.x;
  const int lane = tid & 63;
  const int wid = tid >> 6;
  const int wm = wid >> 1;
  const int wn = wid & 1;

  __shared__ _Float16 Ash[256][40];
  __shared__ _Float16 Asl[256][40];
  __shared__ _Float16 Bsh[128][40];
  __shared__ _Float16 Bsl[128][40];

  f32x4 accm[4][4] = {};
  f32x4 accc[4][4] = {};

  const int arow = tid >> 1;
  const int ako  = (tid & 1) << 4;
  const int nl = tid & 127;
  const int kq = tid >> 7;

  for (int it = 0; it < 128; ++it) {
    const size_t k0 = (size_t)sk * 4096 + it * 32;
    __syncthreads();
    {
      const _Float16* ph = Ahi + (size_t)arow * 262144 + k0 + ako;
      const _Float16* pl = Alo + (size_t)arow * 262144 + k0 + ako;
      *(uint4*)&Ash[arow][ako]     = *(const uint4*)ph;
      *(uint4*)&Ash[arow][ako + 8] = *(const uint4*)(ph + 8);
      *(uint4*)&Asl[arow][ako]     = *(const uint4*)pl;
      *(uint4*)&Asl[arow][ako + 8] = *(const uint4*)(pl + 8);
    }
    {
      const int jbase = (int)k0 + kq * 8;
      f16x8 hv, lv;
#pragma unroll
      for (int i = 0; i < 8; ++i) {
        const int j = jbase + i;
        const size_t wrow = ((size_t)(j & 63) << 12) + (j >> 6);  // NCHW k = oc*4096 + p
        const float f = W[wrow * 1024 + nc0 + nl];
        const _Float16 h = (_Float16)f;
        hv[i] = h;
        lv[i] = (_Float16)((f - (float)h) * 2048.0f);
      }
      *(f16x8*)&Bsh[nl][kq * 8] = hv;
      *(f16x8*)&Bsl[nl][kq * 8] = lv;
    }
    __syncthreads();

    const int ks = (lane >> 4) << 3;
    f16x8 ah[4], al[4], bh[4], bl[4];
#pragma unroll
    for (int mf = 0; mf < 4; ++mf) {
      ah[mf] = *(const f16x8*)&Ash[wm * 64 + mf * 16 + (lane & 15)][ks];
      al[mf] = *(const f16x8*)&Asl[wm * 64 + mf * 16 + (lane & 15)][ks];
    }
#pragma unroll
    for (int nf = 0; nf < 4; ++nf) {
      bh[nf] = *(const f16x8*)&Bsh[wn * 64 + nf * 16 + (lane & 15)][ks];
      bl[nf] = *(const f16x8*)&Bsl[wn * 64 + nf * 16 + (lane & 15)][ks];
    }
#pragma unroll
    for (int mf = 0; mf < 4; ++mf)
#pragma unroll
      for (int nf = 0; nf < 4; ++nf) {
        accm[mf][nf] = __builtin_amdgcn_mfma_f32_16x16x32_f16(ah[mf], bh[nf], accm[mf][nf], 0, 0, 0);
        accc[mf][nf] = __builtin_amdgcn_mfma_f32_16x16x32_f16(ah[mf], bl[nf], accc[mf][nf], 0, 0, 0);
        accc[mf][nf] = __builtin_amdgcn_mfma_f32_16x16x32_f16(al[mf], bh[nf], accc[mf][nf], 0, 0, 0);
      }
  }

#pragma unroll
  for (int mf = 0; mf < 4; ++mf) {
    const int rbase = wm * 64 + mf * 16 + ((lane >> 4) << 2);
#pragma unroll
    for (int nf = 0; nf < 4; ++nf) {
      const int c = nc0 + wn * 64 + nf * 16 + (lane & 15);
#pragma unroll
      for (int r = 0; r < 4; ++r)
        P[((size_t)sk * 256 + rbase + r) * 1024 + c] =
            accm[mf][nf][r] + accc[mf][nf][r] * (1.0f / 2048.0f);
    }
  }
}

// ================= fc1 reduce =================
__global__ __launch_bounds__(256)
void fc1_reduce(const float* __restrict__ P, const float* __restrict__ bias,
                float* __restrict__ s1)
{
  const int idx = blockIdx.x * 256 + threadIdx.x;
  const int n = idx & 1023;
  float a = bias[n];
#pragma unroll 8
  for (int sk = 0; sk < 64; ++sk) a += P[(size_t)sk * 262144 + idx];
  s1[idx] = fmaxf(a, 0.f);
}

// ================= fc2 =================
__global__ __launch_bounds__(256)
void fc2_k(const float* __restrict__ s1, const float* __restrict__ w,
           const float* __restrict__ b, float* __restrict__ s2)
{
  const int bb = blockIdx.x;
  const int t = threadIdx.x;
  __shared__ float xr[1024];
  for (int i = t; i < 1024; i += 256) xr[i] = s1[bb * 1024 + i];
  __syncthreads();
  float a0 = b[t], a1 = 0.f, a2 = 0.f, a3 = 0.f;
#pragma unroll 4
  for (int k = 0; k < 1024; k += 4) {
    a0 += xr[k + 0] * w[(k + 0) * 256 + t];
    a1 += xr[k + 1] * w[(k + 1) * 256 + t];
    a2 += xr[k + 2] * w[(k + 2) * 256 + t];
    a3 += xr[k + 3] * w[(k + 3) * 256 + t];
  }
  s2[bb * 256 + t] = fmaxf(a0 + a1 + a2 + a3, 0.f);
}

// ================= gate =================
__global__ __launch_bounds__(64)
void gate_k(const float* __restrict__ s2, const float* __restrict__ gw,
            const float* __restrict__ gb, float* __restrict__ gate_out,
            int* __restrict__ topi, float* __restrict__ topv)
{
  const int bb = blockIdx.x;
  const int l = threadIdx.x;
  float part[8] = {};
  for (int k = l; k < 256; k += 64) {
    const float x = s2[bb * 256 + k];
#pragma unroll
    for (int e = 0; e < 8; ++e) part[e] += x * gw[k * 8 + e];
  }
#pragma unroll
  for (int off = 32; off > 0; off >>= 1)
#pragma unroll
    for (int e = 0; e < 8; ++e) part[e] += __shfl_down(part[e], off);

  if (l == 0) {
    float lg[8];
    float m = -1e30f;
#pragma unroll
    for (int e = 0; e < 8; ++e) { lg[e] = part[e] + gb[e]; m = fmaxf(m, lg[e]); }
    float s = 0.f;
    float p[8];
#pragma unroll
    for (int e = 0; e < 8; ++e) { p[e] = expf(lg[e] - m); s += p[e]; }
#pragma unroll
    for (int e = 0; e < 8; ++e) { p[e] = p[e] / s; gate_out[bb * 8 + e] = p[e]; }
    int i0 = 0;
#pragma unroll
    for (int e = 1; e < 8; ++e) if (p[e] > p[i0]) i0 = e;
    int i1 = (i0 == 0) ? 1 : 0;
#pragma unroll
    for (int e = 0; e < 8; ++e) if (e != i0 && p[e] > p[i1]) i1 = e;
    const float v0 = p[i0], v1 = p[i1];
    topi[bb * 2 + 0] = i0; topi[bb * 2 + 1] = i1;
    topv[bb * 2 + 0] = v0 / (v0 + v1); topv[bb * 2 + 1] = v1 / (v0 + v1);
  }
}

// ================= experts =================
__global__ __launch_bounds__(256)
void expert_k(const float* __restrict__ s2, const float* __restrict__ w1,
              const float* __restrict__ b1, const float* __restrict__ w2,
              const float* __restrict__ b2, const int* __restrict__ topi,
              const float* __restrict__ topv, float* __restrict__ out)
{
  const int bb = blockIdx.x;
  const int t = threadIdx.x;
  __shared__ float xr[256];
  __shared__ float eh[512];
  __shared__ float partial[18][8];
  xr[t] = s2[bb * 256 + t];
  float logit = 0.f;
  for (int kk = 0; kk < 2; ++kk) {
    __syncthreads();
    const int e = topi[bb * 2 + kk];
    const float tv = topv[bb * 2 + kk];
    const float* W1 = w1 + (size_t)e * 256 * 512;
    float a0 = b1[e * 512 + t], a1 = b1[e * 512 + 256 + t];
#pragma unroll 4
    for (int k = 0; k < 256; ++k) {
      const float x = xr[k];
      a0 = fmaf(x, W1[k * 512 + t], a0);
      a1 = fmaf(x, W1[k * 512 + 256 + t], a1);
    }
    eh[t] = fmaxf(a0, 0.f);
    eh[256 + t] = fmaxf(a1, 0.f);
    __syncthreads();
    if (t < 144) {
      const int a = t >> 3, q = t & 7;
      const float* W2 = w2 + (size_t)e * 512 * 18;
      float pp = 0.f;
      for (int h = q * 64; h < q * 64 + 64; ++h) pp = fmaf(eh[h], W2[h * 18 + a], pp);
      partial[a][q] = pp;
    }
    __syncthreads();
    if (t < 18) {
      float s = b2[e * 18 + t];
#pragma unroll
      for (int q = 0; q < 8; ++q) s += partial[t][q];
      logit = fmaf(tv, s, logit);
    }
  }
  if (t < 18) out[bb * 18 + t] = logit;
}

// ================= launch =================
extern "C" void kernel_launch(void* const* d_in, const int* in_sizes, int n_in,
                              void* d_out, int out_size, void* d_ws, size_t ws_size,
                              hipStream_t stream) {
  const float* obs     = (const float*)d_in[0];
  const float* conv1_w = (const float*)d_in[1];
  const float* conv1_b = (const float*)d_in[2];
  const float* conv2_w = (const float*)d_in[3];
  const float* conv2_b = (const float*)d_in[4];
  const float* conv3_w = (const float*)d_in[5];
  const float* conv3_b = (const float*)d_in[6];
  const float* fc1_w   = (const float*)d_in[7];
  const float* fc1_b   = (const float*)d_in[8];
  const float* fc2_w   = (const float*)d_in[9];
  const float* fc2_b   = (const float*)d_in[10];
  const float* gate_w  = (const float*)d_in[11];
  const float* gate_b  = (const float*)d_in[12];
  const float* exp_w1  = (const float*)d_in[13];
  const float* exp_b1  = (const float*)d_in[14];
  const float* exp_w2  = (const float*)d_in[15];
  const float* exp_b2  = (const float*)d_in[16];

  char* ws = (char*)d_ws;
  const size_t MB = 1ull << 20;
  const size_t KB = 1ull << 10;
  _Float16* act1h = (_Float16*)(ws);                 // 32 MB [256][64][64][16]
  _Float16* act1l = (_Float16*)(ws + 32 * MB);
  _Float16* act2h = (_Float16*)(ws + 64 * MB);       // 64 MB [256][64][64][32]
  _Float16* act2l = (_Float16*)(ws + 128 * MB);
  _Float16* act3h = (_Float16*)(ws + 192 * MB);      // 128 MB [256][64][64][64]
  _Float16* act3l = (_Float16*)(ws + 320 * MB);
  float*    P     = (float*)(ws);                    // 64 MB (reuses act1/act2a after convs)
  _Float16* wp2h  = (_Float16*)(ws + 448 * MB);
  _Float16* wp2l  = (_Float16*)(ws + 448 * MB + 64 * KB);
  _Float16* wp3h  = (_Float16*)(ws + 448 * MB + 128 * KB);
  _Float16* wp3l  = (_Float16*)(ws + 448 * MB + 192 * KB);
  float*    s2    = (float*)(ws + 448 * MB + 256 * KB);
  int*      topi  = (int*)(ws + 448 * MB + 512 * KB);
  float*    topv  = (float*)(ws + 448 * MB + 516 * KB);
  float*    s1    = (float*)(ws + 449 * MB);         // 1 MB
  float*    out   = (float*)d_out;

  prepack_w<<<(32 * 192 + 255) / 256, 256, 0, stream>>>(conv2_w, wp2h, wp2l, 32, 16, 64);
  prepack_w<<<(64 * 288 + 255) / 256, 256, 0, stream>>>(conv3_w, wp3h, wp3l, 64, 32, 96);

  conv1_k<<<dim3(16, 256), 256, 0, stream>>>(obs, conv1_w, conv1_b, act1h, act1l);
  conv_mfma<16, 32><<<dim3(32, 256), 256, 0, stream>>>(act1h, act1l, wp2h, wp2l, conv2_b, act2h, act2l);
  conv_mfma<32, 64><<<dim3(32, 256), 256, 0, stream>>>(act2h, act2l, wp3h, wp3l, conv3_b, act3h, act3l);

  fc1_gemm_split<<<dim3(64, 8), 512, 0, stream>>>(act3h, act3l, fc1_w, P);
  fc1_reduce<<<1024, 256, 0, stream>>>(P, fc1_b, s1);
  fc2_k<<<256, 256, 0, stream>>>(s1, fc2_w, fc2_b, s2);
  gate_k<<<256, 64, 0, stream>>>(s2, gate_w, gate_b, out + 256 * 18, topi, topv);
  expert_k<<<256, 256, 0, stream>>>(s2, exp_w1, exp_b1, exp_w2, exp_b2, topi, topv, out);
}

// Round 4
// 1034.188 us; speedup vs baseline: 1.7711x; 1.1646x over previous
//
#include <hip/hip_runtime.h>

typedef _Float16 f16x8 __attribute__((ext_vector_type(8)));
typedef float f32x4 __attribute__((ext_vector_type(4)));

// ================= weight prepack: OIHW fp32 -> [oc][3*KPAD] split hi/lo f16 =================
__global__ void prepack_w(const float* __restrict__ w, _Float16* __restrict__ ph,
                          _Float16* __restrict__ pl, int COUT, int CIN, int KPAD)
{
  const int idx = blockIdx.x * 256 + threadIdx.x;
  const int KTOT = 3 * KPAD;
  if (idx >= COUT * KTOT) return;
  const int oc = idx / KTOT;
  const int rem = idx - oc * KTOT;
  const int y = rem / KPAD;
  const int kk = rem - y * KPAD;
  float v = 0.f;
  if (kk < 3 * CIN) {
    const int tx = kk / CIN;
    const int ic = kk - tx * CIN;
    v = w[((size_t)oc * CIN + ic) * 9 + y * 3 + tx];
  }
  const _Float16 h = (_Float16)v;
  ph[idx] = h;
  pl[idx] = (_Float16)((v - (float)h) * 2048.0f);
}

// ================= conv1: CIN=1, VALU fp32, NHWC split-f16 out =================
__global__ __launch_bounds__(256)
void conv1_k(const float* __restrict__ obs, const float* __restrict__ w,
             const float* __restrict__ bias, _Float16* __restrict__ outh,
             _Float16* __restrict__ outl)
{
  const int rg = blockIdx.x;
  const int b = blockIdx.y;
  const int tid = threadIdx.x;
  const int lr = tid >> 6;
  const int col = tid & 63;
  __shared__ float xs[6][66];
  __shared__ float wb[9][16];
  for (int idx = tid; idx < 6 * 66; idx += 256) {
    const int r = idx / 66, c = idx - (idx / 66) * 66;
    const int gr = rg * 4 - 1 + r, gc = c - 1;
    xs[r][c] = (gr >= 0 && gr < 64 && gc >= 0 && gc < 64)
                   ? obs[(size_t)b * 4096 + gr * 64 + gc] : 0.f;
  }
  if (tid < 144) wb[tid / 16][tid & 15] = w[(tid & 15) * 9 + tid / 16];
  __syncthreads();
  float acc[16];
#pragma unroll
  for (int o = 0; o < 16; ++o) acc[o] = bias[o];
#pragma unroll
  for (int ty = 0; ty < 3; ++ty)
#pragma unroll
    for (int tx = 0; tx < 3; ++tx) {
      const float x = xs[lr + ty][col + tx];
#pragma unroll
      for (int o = 0; o < 16; ++o) acc[o] = fmaf(x, wb[ty * 3 + tx][o], acc[o]);
    }
  const size_t base = ((size_t)(b * 64 + rg * 4 + lr) * 64 + col) * 16;
#pragma unroll
  for (int o = 0; o < 16; ++o) {
    const float v = fmaxf(acc[o], 0.f);
    const _Float16 h = (_Float16)v;
    outh[base + o] = h;
    outl[base + o] = (_Float16)((v - (float)h) * 2048.0f);
  }
}

// ================= conv MFMA: NHWC shift-GEMM, split-f16 3-term =================
template<int CIN, int COUT>
__global__ __launch_bounds__(256)
void conv_mfma(const _Float16* __restrict__ inh, const _Float16* __restrict__ inl,
               const _Float16* __restrict__ wph, const _Float16* __restrict__ wpl,
               const float* __restrict__ bias,
               _Float16* __restrict__ outh, _Float16* __restrict__ outl)
{
  constexpr int KFX = (3 * CIN + 31) / 32;
  constexpr int KPAD = KFX * 32;
  constexpr int KTOT = 3 * KPAD;
  constexpr int CP = CIN + 8;
  constexpr int NF = COUT / 32;
  const int rp = blockIdx.x;
  const int b  = blockIdx.y;
  const int r0 = rp * 2;
  const int tid = threadIdx.x;
  const int lane = tid & 63;
  const int wid = tid >> 6;
  const int wm = wid >> 1;
  const int wn = wid & 1;

  __shared__ _Float16 xh[4][68][CP];
  __shared__ _Float16 xl[4][68][CP];

  constexpr int CH = CIN / 8;
  for (int idx = tid; idx < 4 * 68 * CH; idx += 256) {
    const int r = idx / (68 * CH);
    const int rem = idx - r * 68 * CH;
    const int hc = rem / CH;
    const int ch = rem - hc * CH;
    const int gr = r0 - 1 + r;
    const int gc = hc - 1;
    uint4 vh = {0, 0, 0, 0}, vl = {0, 0, 0, 0};
    if (gr >= 0 && gr < 64 && gc >= 0 && gc < 64) {
      const size_t base = ((size_t)(b * 64 + gr) * 64 + gc) * CIN + ch * 8;
      vh = *(const uint4*)(inh + base);
      vl = *(const uint4*)(inl + base);
    }
    *(uint4*)&xh[r][hc][ch * 8] = vh;
    *(uint4*)&xl[r][hc][ch * 8] = vl;
  }
  __syncthreads();

  f32x4 accm[4][NF];
  f32x4 accc[4][NF];
#pragma unroll
  for (int mf = 0; mf < 4; ++mf)
#pragma unroll
    for (int nf = 0; nf < NF; ++nf) { accm[mf][nf] = {}; accc[mf][nf] = {}; }

  const int lm = lane & 15;
  const int ch8 = (lane >> 4) * 8;

#pragma unroll
  for (int kf = 0; kf < 3 * KFX; ++kf) {
    const int y = kf / KFX;
    const int fx = kf - y * KFX;
    const int kk = fx * 32 + ch8;
    f16x8 bh[NF], bl[NF];
#pragma unroll
    for (int nf = 0; nf < NF; ++nf) {
      const int oc = wn * (16 * NF) + nf * 16 + lm;
      bh[nf] = *(const f16x8*)(wph + (size_t)oc * KTOT + kf * 32 + ch8);
      bl[nf] = *(const f16x8*)(wpl + (size_t)oc * KTOT + kf * 32 + ch8);
    }
#pragma unroll
    for (int mf = 0; mf < 4; ++mf) {
      const int col = mf * 16 + lm;
      const f16x8 ah = *(const f16x8*)&xh[wm + y][col + kk / CIN][kk % CIN];
      const f16x8 al = *(const f16x8*)&xl[wm + y][col + kk / CIN][kk % CIN];
#pragma unroll
      for (int nf = 0; nf < NF; ++nf) {
        accm[mf][nf] = __builtin_amdgcn_mfma_f32_16x16x32_f16(ah, bh[nf], accm[mf][nf], 0, 0, 0);
        accc[mf][nf] = __builtin_amdgcn_mfma_f32_16x16x32_f16(ah, bl[nf], accc[mf][nf], 0, 0, 0);
        accc[mf][nf] = __builtin_amdgcn_mfma_f32_16x16x32_f16(al, bh[nf], accc[mf][nf], 0, 0, 0);
      }
    }
  }

  const int orow = r0 + wm;
#pragma unroll
  for (int nf = 0; nf < NF; ++nf) {
    const int oc = wn * (16 * NF) + nf * 16 + lm;
    const float bv = bias[oc];
#pragma unroll
    for (int mf = 0; mf < 4; ++mf) {
#pragma unroll
      for (int r = 0; r < 4; ++r) {
        const int x = mf * 16 + (lane >> 4) * 4 + r;
        const float v = fmaxf(accm[mf][nf][r] + accc[mf][nf][r] * (1.0f / 2048.0f) + bv, 0.f);
        const _Float16 h = (_Float16)v;
        const size_t oi = ((size_t)(b * 64 + orow) * 64 + x) * COUT + oc;
        outh[oi] = h;
        outl[oi] = (_Float16)((v - (float)h) * 2048.0f);
      }
    }
  }
}

// ================= fc1 v3: double-buffered, 1 barrier/it, gload_lds A, reg-staged W =================
// grid(32 sk, 8 nt), block 512. K-slice 8192, BK=32, 256 its. LDS 96 KB -> 1 block/CU.
// Linear 64B rows + XOR slot swizzle: slot' = slot ^ ((row>>1)&3) (applied at source AND read).
__global__ __launch_bounds__(512, 2)
void fc1_gemm_v3(const _Float16* __restrict__ Ahi, const _Float16* __restrict__ Alo,
                 const float* __restrict__ W, float* __restrict__ P)
{
  const int sk = blockIdx.x;
  const int nt = blockIdx.y;
  const int nc0 = nt * 128;
  const int tid = threadIdx.x;
  const int lane = tid & 63;
  const int wid = tid >> 6;
  const int wm = wid >> 1;
  const int wn = wid & 1;

  __shared__ _Float16 Ah[2][256][32];
  __shared__ _Float16 Al[2][256][32];
  __shared__ _Float16 Bh[2][128][32];
  __shared__ _Float16 Bl[2][128][32];

  f32x4 accm[4][4] = {};
  f32x4 accc[4][4] = {};

  const int nl = tid & 127;         // B col
  const int kq = tid >> 7;          // B k-slot 0..3
  const int bslot = kq ^ ((nl >> 1) & 3);

  const size_t kbase = (size_t)sk * 8192;
  constexpr int NIT = 256;

  // ---- A stage via global_load_lds with pre-swizzled source ----
  const int Rbase = wid * 32;                    // this wave's 32 rows
  const int lrow0 = Rbase + (lane >> 2);         // call 0 row for this lane
  const int lrow1 = Rbase + 16 + (lane >> 2);    // call 1 row
  const int sd = lane & 3;
  const int ssrc0 = sd ^ ((lrow0 >> 1) & 3);
  const int ssrc1 = sd ^ ((lrow1 >> 1) & 3);
  const size_t goff0 = (size_t)lrow0 * 262144 + ssrc0 * 8;
  const size_t goff1 = (size_t)lrow1 * 262144 + ssrc1 * 8;

#define ISSUE_A(p, k0)                                                                     \
  {                                                                                        \
    __builtin_amdgcn_global_load_lds(                                                      \
        (const __attribute__((address_space(1))) unsigned int*)(Ahi + goff0 + (k0)),       \
        (__attribute__((address_space(3))) unsigned int*)&Ah[p][Rbase][0], 16, 0, 0);      \
    __builtin_amdgcn_global_load_lds(                                                      \
        (const __attribute__((address_space(1))) unsigned int*)(Ahi + goff1 + (k0)),       \
        (__attribute__((address_space(3))) unsigned int*)&Ah[p][Rbase + 16][0], 16, 0, 0); \
    __builtin_amdgcn_global_load_lds(                                                      \
        (const __attribute__((address_space(1))) unsigned int*)(Alo + goff0 + (k0)),       \
        (__attribute__((address_space(3))) unsigned int*)&Al[p][Rbase][0], 16, 0, 0);      \
    __builtin_amdgcn_global_load_lds(                                                      \
        (const __attribute__((address_space(1))) unsigned int*)(Alo + goff1 + (k0)),       \
        (__attribute__((address_space(3))) unsigned int*)&Al[p][Rbase + 16][0], 16, 0, 0); \
  }

#define LOAD_W(k0, wr)                                                     \
  {                                                                        \
    const size_t jb = (k0) + kq * 8;                                       \
    _Pragma("unroll") for (int i = 0; i < 8; ++i) {                        \
      const size_t j = jb + i;                                             \
      const size_t wrow = ((j & 63) << 12) + (j >> 6);                     \
      wr[i] = W[wrow * 1024 + nc0 + nl];                                   \
    }                                                                      \
  }

#define WRITE_B(p, wr)                                                     \
  {                                                                        \
    f16x8 hv, lv;                                                          \
    _Pragma("unroll") for (int i = 0; i < 8; ++i) {                        \
      const _Float16 h = (_Float16)wr[i];                                  \
      hv[i] = h;                                                           \
      lv[i] = (_Float16)((wr[i] - (float)h) * 2048.0f);                    \
    }                                                                      \
    *(f16x8*)&Bh[p][nl][bslot * 8] = hv;                                   \
    *(f16x8*)&Bl[p][nl][bslot * 8] = lv;                                   \
  }

  // prologue: stage it=0 into buf 0
  {
    float wr[8];
    ISSUE_A(0, kbase);
    LOAD_W(kbase, wr);
    WRITE_B(0, wr);
  }
  __syncthreads();

  const int q = lane >> 4;          // k-slot for fragments
  int p = 0;
  for (int it = 0; it < NIT; ++it) {
    float wr[8];
    const bool pf = (it + 1 < NIT);
    if (pf) {
      const size_t k0n = kbase + (size_t)(it + 1) * 32;
      ISSUE_A(p ^ 1, k0n);
      LOAD_W(k0n, wr);
    }

    // compute current buffer
    f16x8 ah[4], al[4], bh[4], bl[4];
#pragma unroll
    for (int mf = 0; mf < 4; ++mf) {
      const int r = wm * 64 + mf * 16 + (lane & 15);
      const int s = (q ^ ((r >> 1) & 3)) * 8;
      ah[mf] = *(const f16x8*)&Ah[p][r][s];
      al[mf] = *(const f16x8*)&Al[p][r][s];
    }
#pragma unroll
    for (int nf = 0; nf < 4; ++nf) {
      const int n = wn * 64 + nf * 16 + (lane & 15);
      const int s = (q ^ ((n >> 1) & 3)) * 8;
      bh[nf] = *(const f16x8*)&Bh[p][n][s];
      bl[nf] = *(const f16x8*)&Bl[p][n][s];
    }
#pragma unroll
    for (int mf = 0; mf < 4; ++mf)
#pragma unroll
      for (int nf = 0; nf < 4; ++nf) {
        accm[mf][nf] = __builtin_amdgcn_mfma_f32_16x16x32_f16(ah[mf], bh[nf], accm[mf][nf], 0, 0, 0);
        accc[mf][nf] = __builtin_amdgcn_mfma_f32_16x16x32_f16(ah[mf], bl[nf], accc[mf][nf], 0, 0, 0);
        accc[mf][nf] = __builtin_amdgcn_mfma_f32_16x16x32_f16(al[mf], bh[nf], accc[mf][nf], 0, 0, 0);
      }

    if (pf) WRITE_B(p ^ 1, wr);
    __syncthreads();
    p ^= 1;
  }
#undef ISSUE_A
#undef LOAD_W
#undef WRITE_B

  // epilogue: C/D layout col=lane&15, row=(lane>>4)*4+r
#pragma unroll
  for (int mf = 0; mf < 4; ++mf) {
    const int rbase = wm * 64 + mf * 16 + ((lane >> 4) << 2);
#pragma unroll
    for (int nf = 0; nf < 4; ++nf) {
      const int c = nc0 + wn * 64 + nf * 16 + (lane & 15);
#pragma unroll
      for (int r = 0; r < 4; ++r)
        P[((size_t)sk * 256 + rbase + r) * 1024 + c] =
            accm[mf][nf][r] + accc[mf][nf][r] * (1.0f / 2048.0f);
    }
  }
}

// ================= fc1 reduce (32 partials) =================
__global__ __launch_bounds__(256)
void fc1_reduce(const float* __restrict__ P, const float* __restrict__ bias,
                float* __restrict__ s1)
{
  const int idx = blockIdx.x * 256 + threadIdx.x;
  const int n = idx & 1023;
  float a = bias[n];
#pragma unroll 8
  for (int sk = 0; sk < 32; ++sk) a += P[(size_t)sk * 262144 + idx];
  s1[idx] = fmaxf(a, 0.f);
}

// ================= fc2 =================
__global__ __launch_bounds__(256)
void fc2_k(const float* __restrict__ s1, const float* __restrict__ w,
           const float* __restrict__ b, float* __restrict__ s2)
{
  const int bb = blockIdx.x;
  const int t = threadIdx.x;
  __shared__ float xr[1024];
  for (int i = t; i < 1024; i += 256) xr[i] = s1[bb * 1024 + i];
  __syncthreads();
  float a0 = b[t], a1 = 0.f, a2 = 0.f, a3 = 0.f;
#pragma unroll 4
  for (int k = 0; k < 1024; k += 4) {
    a0 += xr[k + 0] * w[(k + 0) * 256 + t];
    a1 += xr[k + 1] * w[(k + 1) * 256 + t];
    a2 += xr[k + 2] * w[(k + 2) * 256 + t];
    a3 += xr[k + 3] * w[(k + 3) * 256 + t];
  }
  s2[bb * 256 + t] = fmaxf(a0 + a1 + a2 + a3, 0.f);
}

// ================= gate =================
__global__ __launch_bounds__(64)
void gate_k(const float* __restrict__ s2, const float* __restrict__ gw,
            const float* __restrict__ gb, float* __restrict__ gate_out,
            int* __restrict__ topi, float* __restrict__ topv)
{
  const int bb = blockIdx.x;
  const int l = threadIdx.x;
  float part[8] = {};
  for (int k = l; k < 256; k += 64) {
    const float x = s2[bb * 256 + k];
#pragma unroll
    for (int e = 0; e < 8; ++e) part[e] += x * gw[k * 8 + e];
  }
#pragma unroll
  for (int off = 32; off > 0; off >>= 1)
#pragma unroll
    for (int e = 0; e < 8; ++e) part[e] += __shfl_down(part[e], off);

  if (l == 0) {
    float lg[8];
    float m = -1e30f;
#pragma unroll
    for (int e = 0; e < 8; ++e) { lg[e] = part[e] + gb[e]; m = fmaxf(m, lg[e]); }
    float s = 0.f;
    float p[8];
#pragma unroll
    for (int e = 0; e < 8; ++e) { p[e] = expf(lg[e] - m); s += p[e]; }
#pragma unroll
    for (int e = 0; e < 8; ++e) { p[e] = p[e] / s; gate_out[bb * 8 + e] = p[e]; }
    int i0 = 0;
#pragma unroll
    for (int e = 1; e < 8; ++e) if (p[e] > p[i0]) i0 = e;
    int i1 = (i0 == 0) ? 1 : 0;
#pragma unroll
    for (int e = 0; e < 8; ++e) if (e != i0 && p[e] > p[i1]) i1 = e;
    const float v0 = p[i0], v1 = p[i1];
    topi[bb * 2 + 0] = i0; topi[bb * 2 + 1] = i1;
    topv[bb * 2 + 0] = v0 / (v0 + v1); topv[bb * 2 + 1] = v1 / (v0 + v1);
  }
}

// ================= experts =================
__global__ __launch_bounds__(256)
void expert_k(const float* __restrict__ s2, const float* __restrict__ w1,
              const float* __restrict__ b1, const float* __restrict__ w2,
              const float* __restrict__ b2, const int* __restrict__ topi,
              const float* __restrict__ topv, float* __restrict__ out)
{
  const int bb = blockIdx.x;
  const int t = threadIdx.x;
  __shared__ float xr[256];
  __shared__ float eh[512];
  __shared__ float partial[18][8];
  xr[t] = s2[bb * 256 + t];
  float logit = 0.f;
  for (int kk = 0; kk < 2; ++kk) {
    __syncthreads();
    const int e = topi[bb * 2 + kk];
    const float tv = topv[bb * 2 + kk];
    const float* W1 = w1 + (size_t)e * 256 * 512;
    float a0 = b1[e * 512 + t], a1 = b1[e * 512 + 256 + t];
#pragma unroll 4
    for (int k = 0; k < 256; ++k) {
      const float x = xr[k];
      a0 = fmaf(x, W1[k * 512 + t], a0);
      a1 = fmaf(x, W1[k * 512 + 256 + t], a1);
    }
    eh[t] = fmaxf(a0, 0.f);
    eh[256 + t] = fmaxf(a1, 0.f);
    __syncthreads();
    if (t < 144) {
      const int a = t >> 3, q2 = t & 7;
      const float* W2 = w2 + (size_t)e * 512 * 18;
      float pp = 0.f;
      for (int h = q2 * 64; h < q2 * 64 + 64; ++h) pp = fmaf(eh[h], W2[h * 18 + a], pp);
      partial[a][q2] = pp;
    }
    __syncthreads();
    if (t < 18) {
      float s = b2[e * 18 + t];
#pragma unroll
      for (int q2 = 0; q2 < 8; ++q2) s += partial[t][q2];
      logit = fmaf(tv, s, logit);
    }
  }
  if (t < 18) out[bb * 18 + t] = logit;
}

// ================= launch =================
extern "C" void kernel_launch(void* const* d_in, const int* in_sizes, int n_in,
                              void* d_out, int out_size, void* d_ws, size_t ws_size,
                              hipStream_t stream) {
  const float* obs     = (const float*)d_in[0];
  const float* conv1_w = (const float*)d_in[1];
  const float* conv1_b = (const float*)d_in[2];
  const float* conv2_w = (const float*)d_in[3];
  const float* conv2_b = (const float*)d_in[4];
  const float* conv3_w = (const float*)d_in[5];
  const float* conv3_b = (const float*)d_in[6];
  const float* fc1_w   = (const float*)d_in[7];
  const float* fc1_b   = (const float*)d_in[8];
  const float* fc2_w   = (const float*)d_in[9];
  const float* fc2_b   = (const float*)d_in[10];
  const float* gate_w  = (const float*)d_in[11];
  const float* gate_b  = (const float*)d_in[12];
  const float* exp_w1  = (const float*)d_in[13];
  const float* exp_b1  = (const float*)d_in[14];
  const float* exp_w2  = (const float*)d_in[15];
  const float* exp_b2  = (const float*)d_in[16];

  char* ws = (char*)d_ws;
  const size_t MB = 1ull << 20;
  const size_t KB = 1ull << 10;
  _Float16* act1h = (_Float16*)(ws);                 // 32 MB [256][64][64][16]
  _Float16* act1l = (_Float16*)(ws + 32 * MB);
  _Float16* act2h = (_Float16*)(ws + 64 * MB);       // 64 MB [256][64][64][32]
  _Float16* act2l = (_Float16*)(ws + 128 * MB);
  _Float16* act3h = (_Float16*)(ws + 192 * MB);      // 128 MB [256][64][64][64]
  _Float16* act3l = (_Float16*)(ws + 320 * MB);
  float*    P     = (float*)(ws);                    // 32 MB [32][256][1024] (reuses act1)
  _Float16* wp2h  = (_Float16*)(ws + 448 * MB);
  _Float16* wp2l  = (_Float16*)(ws + 448 * MB + 64 * KB);
  _Float16* wp3h  = (_Float16*)(ws + 448 * MB + 128 * KB);
  _Float16* wp3l  = (_Float16*)(ws + 448 * MB + 192 * KB);
  float*    s2    = (float*)(ws + 448 * MB + 256 * KB);
  int*      topi  = (int*)(ws + 448 * MB + 512 * KB);
  float*    topv  = (float*)(ws + 448 * MB + 516 * KB);
  float*    s1    = (float*)(ws + 449 * MB);         // 1 MB
  float*    out   = (float*)d_out;

  prepack_w<<<(32 * 192 + 255) / 256, 256, 0, stream>>>(conv2_w, wp2h, wp2l, 32, 16, 64);
  prepack_w<<<(64 * 288 + 255) / 256, 256, 0, stream>>>(conv3_w, wp3h, wp3l, 64, 32, 96);

  conv1_k<<<dim3(16, 256), 256, 0, stream>>>(obs, conv1_w, conv1_b, act1h, act1l);
  conv_mfma<16, 32><<<dim3(32, 256), 256, 0, stream>>>(act1h, act1l, wp2h, wp2l, conv2_b, act2h, act2l);
  conv_mfma<32, 64><<<dim3(32, 256), 256, 0, stream>>>(act2h, act2l, wp3h, wp3l, conv3_b, act3h, act3l);

  fc1_gemm_v3<<<dim3(32, 8), 512, 0, stream>>>(act3h, act3l, fc1_w, P);
  fc1_reduce<<<1024, 256, 0, stream>>>(P, fc1_b, s1);
  fc2_k<<<256, 256, 0, stream>>>(s1, fc2_w, fc2_b, s2);
  gate_k<<<256, 64, 0, stream>>>(s2, gate_w, gate_b, out + 256 * 18, topi, topv);
  expert_k<<<256, 256, 0, stream>>>(s2, exp_w1, exp_b1, exp_w2, exp_b2, topi, topv, out);
}